// Round 11
// baseline (301.074 us; speedup 1.0000x reference)
//
#include <hip/hip_runtime.h>

// SSIM (window=8 box sums) over 96 images of 512x512 fp32.
// v16: 1-col-per-lane, barrier-free, register-ring, near-compulsory bytes.
//  - Ten-round synthesis: barrier-free wave structures deliver 3.9-4.2 TB/s
//    (v10-v13) but paid 1.65x bytes for the ring they couldn't afford
//    (8 cols/lane -> 128 VGPR).  LDS structures are byte-minimal but
//    barrier-coupled at ~2.3 TB/s (v8/v14/v15).  v16 combines: 1 col/lane
//    -> ring = 8 rows x 2 imgs x 1 float = 16 VGPR, NO LDS, NO barriers.
//  - Horizontal 8-window via 3-step shuffle prefix (down 1,2,4) == the
//    balanced tree that already passed bit-exact in v9-v13.
//  - Geometry: 9 slabs of 64 cols (57 outputs each, 7-col overlap) x
//    4 vertical splits (127/127/127/124 outputs, 7-row overlap) x 96 imgs
//    = 3456 waves (13.5/CU).  Bytes = 201 MB x1.125 x1.055 ~= 239 MB.
//  - Depth-4 scalar prefetch ring (8 VGPR): slot k&3 consumed at output o,
//    refilled with row o+11 for output o+4 -> consumed loads are always
//    the OLDEST outstanding (6 younger) -> counted vmcnt (v12 lesson).
//  - XCD swizzle: 3456 = 8*432; each XCD gets 12 contiguous images; the
//    36 waves of an image co-run on one XCD -> overlap re-reads L2-hit.
// Tripwires: WRITE_SIZE >> 96 KB => spill; VGPR ~60-80 expected.

#define W 512
#define H 512
#define OW 505
#define OH 505
#define NIMG 96
#define NSLAB 9                       // x0 = 57*slab; slab 8 has 49 outputs
#define NSPLIT 4                      // r0 = 127*split; split 3 has 124 rows
#define NWG (NSLAB * NSPLIT * NIMG)   // 3456 = 8 * 432
#define NPIX (96.0 * 505.0 * 505.0)   // 24482400

__global__ void finalize(const double* p, float* out) {
    out[0] = 1.0f - (float)(*p / NPIX);
}

__global__ void __launch_bounds__(64)
ssim_main(const float* __restrict__ gt, const float* __restrict__ ni,
          double* __restrict__ acc_out)
{
    const int l = threadIdx.x;        // 0..63, owns one column

    // XCD swizzle: HW XCD = blockIdx%8; give each XCD 432 contiguous wids
    // = 12 whole images (36 waves/image co-resident on one XCD's L2).
    const int b     = blockIdx.x;
    const int wid   = (b & 7) * (NWG / 8) + (b >> 3);
    const int img   = wid / (NSLAB * NSPLIT);
    const int rem   = wid % (NSLAB * NSPLIT);
    const int slab  = rem % NSLAB;
    const int split = rem / NSLAB;

    const int x0   = slab * 57;
    const int col  = x0 + l;
    const int cole = min(col, W - 1);       // clamp: lanes>=57 of slab 8 read
                                            // col 511 garbage, predicated out
    const int cmax = min(x0 + 57, OW);      // valid outputs: col < cmax
    const bool valid = col < cmax;          // (l<57 and col<505)

    const int r0 = split * 127;
    const int R1 = min(r0 + 127, OH);       // outputs r0..R1-1 (>=124 rows)

    const float C1 = 1e-4f;
    const float C2 = 9e-4f;

    const float* gx = gt + (size_t)img * (W * H) + cole;
    const float* gy = ni + (size_t)img * (W * H) + cole;

    // 8-row register ring (literal-indexed only) + vertical window sums
    float rgx[8], rgy[8];
    float vsx = 0.f, vsy = 0.f, vsq = 0.f, vsp = 0.f;

    // depth-4 prefetch slots (literal-indexed only)
    float pfx[4], pfy[4];

    // ---- warmup: issue rows r0..r0+6 and prime pf rows r0+7..r0+10 ----
    float wx[7], wy[7];
#pragma unroll
    for (int k = 0; k < 7; ++k) {
        wx[k] = gx[(size_t)(r0 + k) * W];
        wy[k] = gy[(size_t)(r0 + k) * W];
    }
#pragma unroll
    for (int s = 0; s < 4; ++s) {           // rows <= 381+10 = 391 < 512
        pfx[s] = gx[(size_t)(r0 + 7 + s) * W];
        pfy[s] = gy[(size_t)(r0 + 7 + s) * W];
    }
#pragma unroll
    for (int k = 0; k < 7; ++k) {           // same add order as v8/v9
        float cx = wx[k], cy = wy[k];
        rgx[k] = cx; rgy[k] = cy;
        vsx += cx; vsy += cy;
        vsq += cx * cx + cy * cy;
        vsp += cx * cy;
    }
    rgx[7] = 0.f; rgy[7] = 0.f;             // virtual row r0-1 = zeros

    float acc = 0.0f;

// horizontal 8-window via shuffle prefix (down 1,2,4) -- balanced tree
// identical to v9's HORIZ order: ((0+1)+(2+3))+((4+5)+(6+7)), over
// CONSECUTIVE columns l..l+7.  Lanes >=57 get garbage, predicated out.
#define PREFIX_SSIM() {                                                   \
        float s1x = vsx + __shfl_down(vsx, 1);                            \
        float s1y = vsy + __shfl_down(vsy, 1);                            \
        float s1q = vsq + __shfl_down(vsq, 1);                            \
        float s1p = vsp + __shfl_down(vsp, 1);                            \
        float s2x = s1x + __shfl_down(s1x, 2);                            \
        float s2y = s1y + __shfl_down(s1y, 2);                            \
        float s2q = s1q + __shfl_down(s1q, 2);                            \
        float s2p = s1p + __shfl_down(s1p, 2);                            \
        float Sx  = s2x + __shfl_down(s2x, 4);                            \
        float Sy  = s2y + __shfl_down(s2y, 4);                            \
        float Sq  = s2q + __shfl_down(s2q, 4);                            \
        float Sp  = s2p + __shfl_down(s2p, 4);                            \
        float mu12 = Sx * Sy;                                             \
        float n1v = 2.0f * mu12 + C1;                                     \
        float n2v = 2.0f * (Sp - mu12) + C2;                              \
        float sx2 = Sx * Sx, sy2 = Sy * Sy;                               \
        float d1  = sx2 + sy2 + C1;                                       \
        float d2  = (Sq - sx2 - sy2) + C2;                                \
        float sv  = (n1v * n2v) * __builtin_amdgcn_rcpf(d1 * d2);         \
        if (valid) acc += sv;                                             \
    }

// one output row o = rb+k (k literal 0..7):
//  - consume pf slot k&3 (row o+7), outgoing ring slot (k+7)&7 (row o-1)
//  - refill slot k&3 with row o+11 for output o+4 (guard matches consumer
//    exactly: that output runs iff o+4 < R1).  Max row o+11 <= R1+6 <= 511.
//  - consumed slot's loads are the oldest outstanding (slots of k-1..k-3
//    = 6 loads younger) -> compiler can emit counted vmcnt, no drain.
#define ROW(k) {                                                          \
        const int o = rb + (k);                                           \
        if (o < R1) { /* wave-uniform */                                  \
            float cx = pfx[(k) & 3], cy = pfy[(k) & 3];                   \
            float ox = rgx[((k) + 7) & 7], oy = rgy[((k) + 7) & 7];       \
            vsx = (vsx - ox) + cx;                                        \
            vsy = (vsy - oy) + cy;                                        \
            vsq = vsq + ((cx * cx + cy * cy) - (ox * ox + oy * oy));      \
            vsp = vsp + (cx * cy - ox * oy);                              \
            rgx[((k) + 7) & 7] = cx; rgy[((k) + 7) & 7] = cy;             \
            if (o + 4 < R1) {                                             \
                pfx[(k) & 3] = gx[(size_t)(o + 11) * W];                  \
                pfy[(k) & 3] = gy[(size_t)(o + 11) * W];                  \
            }                                                             \
            PREFIX_SSIM()                                                 \
        }                                                                 \
    }

    // main loop: octets of output rows.  Ring slot mapping is relative to
    // r0 (slot (k+7)&7 cycles with period 8 = ring period), so r0 need not
    // be 8-aligned.  First output consumes ring slot 7 (zeros), matching
    // v8's warmup semantics bit-exactly ((vs-0)+cx == vs+cx).
    for (int rb = r0; rb < R1; rb += 8) {
        ROW(0) ROW(1) ROW(2) ROW(3) ROW(4) ROW(5) ROW(6) ROW(7)
    }

    // ---- reduction: single wave -> one double atomic ----
#pragma unroll
    for (int off = 32; off > 0; off >>= 1) acc += __shfl_down(acc, off);
    if (l == 0) atomicAdd(acc_out, (double)acc);
}

extern "C" void kernel_launch(void* const* d_in, const int* in_sizes, int n_in,
                              void* d_out, int out_size, void* d_ws, size_t ws_size,
                              hipStream_t stream) {
    const float* gt = (const float*)d_in[0];
    const float* ni = (const float*)d_in[1];
    double* acc = (double*)d_ws;   // 8 bytes scratch, re-poisoned every call

    hipMemsetAsync(acc, 0, sizeof(double), stream);
    ssim_main<<<dim3(NWG), 64, 0, stream>>>(gt, ni, acc);
    finalize<<<1, 1, 0, stream>>>(acc, (float*)d_out);
}